// Round 13
// baseline (85.920 us; speedup 1.0000x reference)
//
#include <hip/hip_runtime.h>

#define BB 8
#define LL 32768
#define DD 64

typedef float f4 __attribute__((ext_vector_type(4)));
typedef unsigned long long u64x2 __attribute__((ext_vector_type(2)));

// ws layout:
// [0, 256K)        : double part[BB][CHUNKS_Q][DD]   (fully written by k1)
// [256K, 256K+2M)  : double scores[BB*LL]            (fully written by k2)
// aux = 256K+2M:
//   [aux+0,   +64)   : u64 gAnd[BB]   (init ~0 by k1, atomicAnd by k2)
//   [aux+64,  +128)  : u64 gOr[BB]    (init 0 by k1, atomicOr by k2)
//   [aux+128, +160)  : u32 gcnt[BB]   (init 0 by k1, atomicAdd by k_filter)
//   [aux+256, +128K) : u64 candKey[BB][CAP]
//   [.. +64K)        : u32 candIdx[BB][CAP]

#define OUT_F4 (BB * LL * DD / 4)
#define CHUNKS_Q 64
#define ROWS_Q (LL / CHUNKS_Q)
#define CAP 2048
#define NCOPY 16
#define HSTRIDE 257
#define MAXSEL 96

// ---------------- Kernel 1: per-chunk partials of sum_l relu(q)+eps ----------------
__global__ __launch_bounds__(256) void k_reduce_q(const float* __restrict__ q,
                                                  double* __restrict__ part,
                                                  float* __restrict__ out,
                                                  unsigned long long* __restrict__ gAnd,
                                                  unsigned long long* __restrict__ gOr,
                                                  unsigned int* __restrict__ gcnt) {
    if (blockIdx.x < BB && threadIdx.x == 0) {
        gAnd[blockIdx.x] = ~0ULL;
        gOr[blockIdx.x]  = 0ULL;
        gcnt[blockIdx.x] = 0u;
    }
    {
        f4 z = (f4)(0.0f);
        f4* oz = (f4*)out + (size_t)blockIdx.x * 4096 + threadIdx.x;
#pragma unroll
        for (int i = 0; i < 16; ++i) oz[i * 256] = z;
    }

    int b     = blockIdx.x >> 6;
    int chunk = blockIdx.x & (CHUNKS_Q - 1);
    int quad  = threadIdx.x & 15;
    int rowg  = threadIdx.x >> 4;

    const f4* qb = (const f4*)(q + (size_t)b * LL * DD);
    const f4* base = qb + (size_t)(chunk * ROWS_Q + rowg) * 16 + quad;

    double a0 = 0.0, a1 = 0.0, a2 = 0.0, a3 = 0.0;
    f4 vb[8];
#pragma unroll
    for (int batch = 0; batch < 4; ++batch) {
#pragma unroll
        for (int j = 0; j < 8; ++j)
            vb[j] = base[(size_t)(batch * 8 + j) * 256];
#pragma unroll
        for (int j = 0; j < 8; ++j) {
            a0 += (double)fmaxf(vb[j].x, 0.0f) + 1e-3;
            a1 += (double)fmaxf(vb[j].y, 0.0f) + 1e-3;
            a2 += (double)fmaxf(vb[j].z, 0.0f) + 1e-3;
            a3 += (double)fmaxf(vb[j].w, 0.0f) + 1e-3;
        }
    }

    __shared__ double lds[16][16][5];
    lds[rowg][quad][0] = a0; lds[rowg][quad][1] = a1;
    lds[rowg][quad][2] = a2; lds[rowg][quad][3] = a3;
    __syncthreads();
    for (int s = 8; s > 0; s >>= 1) {
        if (rowg < s) {
            lds[rowg][quad][0] += lds[rowg + s][quad][0];
            lds[rowg][quad][1] += lds[rowg + s][quad][1];
            lds[rowg][quad][2] += lds[rowg + s][quad][2];
            lds[rowg][quad][3] += lds[rowg + s][quad][3];
        }
        __syncthreads();
    }
    if (rowg == 0) {
        double* pp = part + ((size_t)b * CHUNKS_Q + chunk) * DD;
        pp[quad * 4 + 0] = lds[0][quad][0];
        pp[quad * 4 + 1] = lds[0][quad][1];
        pp[quad * 4 + 2] = lds[0][quad][2];
        pp[quad * 4 + 3] = lds[0][quad][3];
    }
}

// ---------------- Kernel 2: reduce partials -> rq, scores + global AND/OR ----------------
__global__ __launch_bounds__(256) void k_scores(const float* __restrict__ k,
                                                const double* __restrict__ part,
                                                double* __restrict__ scores,
                                                float* __restrict__ out,
                                                unsigned long long* __restrict__ gAnd,
                                                unsigned long long* __restrict__ gOr) {
    __shared__ double s_part[4][DD];
    __shared__ double s_rq[DD];
    __shared__ unsigned long long sA2[4], sO2[4];

    {
        f4 z = (f4)(0.0f);
        f4* oz = (f4*)out + (size_t)(OUT_F4 / 2)
               + (size_t)blockIdx.x * 2048 + threadIdx.x;
#pragma unroll
        for (int i = 0; i < 8; ++i) oz[i * 256] = z;
    }

    const int RPB = 256;
    int b     = blockIdx.x >> 7;
    int chunk = blockIdx.x & 127;

    {
        int d = threadIdx.x & 63;
        int g = threadIdx.x >> 6;
        const double* pp = part + (size_t)b * CHUNKS_Q * DD;
        double acc = 0.0;
#pragma unroll
        for (int j = 0; j < 16; ++j)
            acc += pp[(size_t)(g * 16 + j) * DD + d];
        s_part[g][d] = acc;
    }
    __syncthreads();
    if (threadIdx.x < DD) {
        int d = threadIdx.x;
        s_rq[d] = (s_part[0][d] + s_part[1][d]) + (s_part[2][d] + s_part[3][d]);
    }
    __syncthreads();

    int sub   = threadIdx.x & 15;
    int rowIn = threadIdx.x >> 4;

    double r0 = s_rq[sub * 4 + 0];
    double r1 = s_rq[sub * 4 + 1];
    double r2 = s_rq[sub * 4 + 2];
    double r3 = s_rq[sub * 4 + 3];

    const f4* kb = (const f4*)(k + (size_t)b * LL * DD);
    int l0 = chunk * RPB;
    const f4* base = kb + (size_t)(l0 + rowIn) * 16 + sub;

    unsigned long long ma = ~0ULL, mo = 0ULL;
    f4 vb[8];
    double sv[8];
#pragma unroll
    for (int batch = 0; batch < 2; ++batch) {
#pragma unroll
        for (int i = 0; i < 8; ++i)
            vb[i] = base[(size_t)(batch * 8 + i) * 256];
#pragma unroll
        for (int i = 0; i < 8; ++i) {
            sv[i] = r0 * ((double)fmaxf(vb[i].x, 0.0f) + 1e-3)
                  + r1 * ((double)fmaxf(vb[i].y, 0.0f) + 1e-3)
                  + r2 * ((double)fmaxf(vb[i].z, 0.0f) + 1e-3)
                  + r3 * ((double)fmaxf(vb[i].w, 0.0f) + 1e-3);
        }
#pragma unroll
        for (int i = 0; i < 8; ++i) {
            double s = sv[i];
            s += __shfl_xor(s, 1, 16);
            s += __shfl_xor(s, 2, 16);
            s += __shfl_xor(s, 4, 16);
            s += __shfl_xor(s, 8, 16);
            if (sub == 0) {
                scores[(size_t)b * LL + l0 + rowIn + 16 * (batch * 8 + i)] = s;
                unsigned long long u = (unsigned long long)__double_as_longlong(s);
                ma &= u; mo |= u;
            }
        }
    }

    // block AND/OR reduce -> 2 global atomics
#pragma unroll
    for (int off = 32; off >= 1; off >>= 1) {
        ma &= __shfl_xor(ma, off);
        mo |= __shfl_xor(mo, off);
    }
    if ((threadIdx.x & 63) == 0) { sA2[threadIdx.x >> 6] = ma; sO2[threadIdx.x >> 6] = mo; }
    __syncthreads();
    if (threadIdx.x == 0) {
        unsigned long long a = sA2[0] & sA2[1] & sA2[2] & sA2[3];
        unsigned long long o = sO2[0] | sO2[1] | sO2[2] | sO2[3];
        atomicAnd(&gAnd[b], a);
        atomicOr(&gOr[b], o);
    }
}

// ---------------- Kernel 3a: parallel candidate filter (128 blocks, 16/batch) ----------------
// Keep key iff fewer than (top_k+1) keys IN THIS BLOCK have a strictly greater
// 11-bit digit at the first globally-live byte -> superset of global top-(top_k+1).
__global__ __launch_bounds__(256) void k_filter(const double* __restrict__ scores,
                                                const unsigned long long* __restrict__ gAnd,
                                                const unsigned long long* __restrict__ gOr,
                                                const int* __restrict__ topk_p,
                                                unsigned int* __restrict__ gcnt,
                                                unsigned long long* __restrict__ candKey,
                                                unsigned int* __restrict__ candIdx) {
    int b   = blockIdx.x >> 4;
    int s   = blockIdx.x & 15;
    int tid = threadIdx.x;
    unsigned long long A = gAnd[b], O = gOr[b];
    if (A == O) return;   // all keys equal: nothing selected, gcnt stays 0

    int sB = 0;
    for (int sh = 56; sh >= 0; sh -= 8)
        if ((((A >> sh) ^ (O >> sh)) & 255ULL) != 0ULL) { sB = sh; break; }
    int shift2 = (sB >= 3) ? (sB - 3) : 0;
    unsigned int K1 = (unsigned int)topk_p[0] + 1u;

    const u64x2* sb2 = (const u64x2*)(scores + (size_t)b * LL);
    u64x2 p[4];
#pragma unroll
    for (int j = 0; j < 4; ++j) p[j] = sb2[(size_t)s * 1024 + tid + j * 256];

    __shared__ unsigned int hist[2048];      // digit counts, then suffix S(d)
    __shared__ unsigned long long sKey[2048];
    __shared__ unsigned int sIdx[2048];
    __shared__ unsigned int sW[4];
    __shared__ unsigned int s_loc, s_base;
    for (int i = tid; i < 2048; i += 256) hist[i] = 0;
    if (tid == 0) s_loc = 0;
    __syncthreads();
#pragma unroll
    for (int j = 0; j < 4; ++j) {
        atomicAdd(&hist[(unsigned)(p[j].x >> shift2) & 2047u], 1u);
        atomicAdd(&hist[(unsigned)(p[j].y >> shift2) & 2047u], 1u);
    }
    __syncthreads();

    // suffix S(d) = # local keys with digit >= d, over 2048 bins (8 per thread)
    unsigned int h[8], sl[8];
#pragma unroll
    for (int j = 0; j < 8; ++j) h[j] = hist[tid * 8 + j];
    unsigned int run = 0;
#pragma unroll
    for (int j = 7; j >= 0; --j) { run += h[j]; sl[j] = run; }
    unsigned int tot = run, vv = tot;
    int lane = tid & 63;
#pragma unroll
    for (int off = 1; off < 64; off <<= 1) {
        unsigned int t = __shfl_down(vv, off);
        if (lane + off < 64) vv += t;
    }
    if (lane == 0) sW[tid >> 6] = vv;
    __syncthreads();
    unsigned int add = 0;
    int w = tid >> 6;
#pragma unroll
    for (int ww = 0; ww < 4; ++ww) if (ww > w) add += sW[ww];
    unsigned int above = (vv + add) - tot;   // suffix of strictly higher threads' bins
    __syncthreads();
#pragma unroll
    for (int j = 0; j < 8; ++j) hist[tid * 8 + j] = above + sl[j];   // hist[d] = S(d)
    __syncthreads();

    // keep test + LDS staging
#pragma unroll
    for (int j = 0; j < 4; ++j) {
        unsigned long long kx = p[j].x;
        unsigned int dx = (unsigned)(kx >> shift2) & 2047u;
        if (dx == 2047u || hist[dx + 1] < K1) {
            unsigned int sl2 = atomicAdd(&s_loc, 1u);
            sKey[sl2] = kx;
            sIdx[sl2] = 2u * ((unsigned)s * 1024u + (unsigned)tid + (unsigned)j * 256u);
        }
        unsigned long long ky = p[j].y;
        unsigned int dy = (unsigned)(ky >> shift2) & 2047u;
        if (dy == 2047u || hist[dy + 1] < K1) {
            unsigned int sl2 = atomicAdd(&s_loc, 1u);
            sKey[sl2] = ky;
            sIdx[sl2] = 2u * ((unsigned)s * 1024u + (unsigned)tid + (unsigned)j * 256u) + 1u;
        }
    }
    __syncthreads();
    if (tid == 0) s_base = atomicAdd(&gcnt[b], s_loc);
    __syncthreads();
    unsigned int nb = s_loc, base2 = s_base;
    for (unsigned int i = tid; i < nb; i += 256) {
        unsigned int g = base2 + i;
        if (g < CAP) {
            candKey[(size_t)b * CAP + g] = sKey[i];
            candIdx[(size_t)b * CAP + g] = sIdx[i];
        }
    }
}

// shared 256-bin rank-scan used by both k_select_gather paths
#define RADIX_SCAN(RVAR)                                                        \
    {                                                                           \
        unsigned int suf = 0, sufn = 0;                                         \
        if (tid < 256) {                                                        \
            unsigned int vtot = 0;                                              \
            _Pragma("unroll")                                                   \
            for (int c = 0; c < NCOPY; ++c) vtot += hist[c * HSTRIDE + tid];    \
            unsigned int vv2 = vtot;                                            \
            int lane2 = tid & 63;                                               \
            _Pragma("unroll")                                                   \
            for (int off = 1; off < 64; off <<= 1) {                            \
                unsigned int t2 = __shfl_down(vv2, off);                        \
                if (lane2 + off < 64) vv2 += t2;                                \
            }                                                                   \
            if (lane2 == 0) sWaveTot[tid >> 6] = vv2;                           \
            suf = vv2;                                                          \
        }                                                                       \
        __syncthreads();                                                        \
        if (tid < 256) {                                                        \
            int lane2 = tid & 63, w2 = tid >> 6;                                \
            unsigned int add2 = 0;                                              \
            _Pragma("unroll")                                                   \
            for (int ww = 0; ww < 4; ++ww) if (ww > w2) add2 += sWaveTot[ww];   \
            unsigned int nsuf = __shfl_down(suf, 1);                            \
            suf += add2;                                                        \
            sufn = ((lane2 == 63) ? 0u : nsuf) + add2;                          \
            if (suf > (unsigned int)(RVAR) && sufn <= (unsigned int)(RVAR)) {   \
                sh_digit = tid;                                                 \
                sh_newr  = (RVAR) - (int)sufn;                                  \
                sh_cnt   = (int)(suf - sufn);                                   \
            }                                                                   \
        }                                                                       \
        __syncthreads();                                                        \
    }

// ---------------- Kernel 3b: exact select among candidates + gather ----------------
__global__ __launch_bounds__(1024) void k_select_gather(
        const double* __restrict__ scores,
        const unsigned long long* __restrict__ gAnd,
        const unsigned long long* __restrict__ gOr,
        const unsigned int* __restrict__ gcnt,
        const unsigned long long* __restrict__ candKey,
        const unsigned int* __restrict__ candIdx,
        const int* __restrict__ topk_p,
        const float* __restrict__ v,
        float* __restrict__ out) {
    const int T = 1024;
    int b = blockIdx.x, tid = threadIdx.x;
    unsigned long long A = gAnd[b], O = gOr[b];
    if (A == O) return;  // degenerate: strict > selects nothing; out already zero

    __shared__ unsigned int hist[NCOPY * HSTRIDE];
    __shared__ unsigned long long sA16[16], sO16[16];
    __shared__ unsigned int sWaveTot[4];
    __shared__ unsigned long long sh_prefix, cA, cO;
    __shared__ int sh_r, sh_digit, sh_newr, sh_cnt, sh_done;
    __shared__ int s_cnt;
    __shared__ int s_idx[MAXSEL];

    unsigned int n0 = gcnt[b];
    if (n0 == 0) return;

    if (n0 <= CAP) {
        // ---------- candidate path (keys in 2 named regs/thread, no arrays) ----------
        bool v0 = tid < (int)n0, v1 = tid + T < (int)n0;
        unsigned long long c0 = v0 ? candKey[(size_t)b * CAP + tid] : 0ULL;
        unsigned long long c1 = v1 ? candKey[(size_t)b * CAP + tid + T] : 0ULL;
        unsigned int i0 = v0 ? candIdx[(size_t)b * CAP + tid] : 0u;
        unsigned int i1 = v1 ? candIdx[(size_t)b * CAP + tid + T] : 0u;

        unsigned long long ma = ~0ULL, mo = 0ULL;
        if (v0) { ma &= c0; mo |= c0; }
        if (v1) { ma &= c1; mo |= c1; }
#pragma unroll
        for (int off = 32; off >= 1; off >>= 1) {
            ma &= __shfl_xor(ma, off);
            mo |= __shfl_xor(mo, off);
        }
        if ((tid & 63) == 0) { sA16[tid >> 6] = ma; sO16[tid >> 6] = mo; }
        __syncthreads();
        if (tid == 0) {
            unsigned long long a = ~0ULL, o = 0ULL;
#pragma unroll
            for (int w2 = 0; w2 < 16; ++w2) { a &= sA16[w2]; o |= sO16[w2]; }
            cA = a; cO = o;
            sh_prefix = 0ULL; sh_r = topk_p[0]; sh_done = 0;
        }
        __syncthreads();

        int copy = tid & (NCOPY - 1);
        bool f0 = v0, f1 = v1;

        for (int shift = 56; shift >= 0; shift -= 8) {
            if (sh_done) break;
            unsigned int dA2 = (unsigned int)(cA >> shift) & 255u;
            unsigned int dO2 = (unsigned int)(cO >> shift) & 255u;
            if (dA2 == dO2) {
                if (tid == 0) sh_prefix |= ((unsigned long long)dA2 << shift);
                __syncthreads();
                continue;
            }
            for (int i = tid; i < NCOPY * HSTRIDE; i += T) hist[i] = 0;
            __syncthreads();
            int r = sh_r;
            if (f0) atomicAdd(&hist[copy * HSTRIDE + ((unsigned)(c0 >> shift) & 255u)], 1u);
            if (f1) atomicAdd(&hist[copy * HSTRIDE + ((unsigned)(c1 >> shift) & 255u)], 1u);
            __syncthreads();
            RADIX_SCAN(r)
            if (tid == 0) {
                sh_prefix |= ((unsigned long long)sh_digit << shift);
                sh_r = sh_newr;
            }
            __syncthreads();
            unsigned int dsel = (unsigned int)sh_digit;
            if (f0 && (((unsigned)(c0 >> shift) & 255u) != dsel)) f0 = false;
            if (f1 && (((unsigned)(c1 >> shift) & 255u) != dsel)) f1 = false;
            if (sh_cnt == 1) {
                if (f0)      { sh_prefix = c0; sh_done = 1; }
                else if (f1) { sh_prefix = c1; sh_done = 1; }
            }
            __syncthreads();
        }

        unsigned long long cb = sh_prefix;
        if (tid == 0) s_cnt = 0;
        __syncthreads();
        if (v0 && c0 > cb) { int sl = atomicAdd(&s_cnt, 1); if (sl < MAXSEL) s_idx[sl] = (int)i0; }
        if (v1 && c1 > cb) { int sl = atomicAdd(&s_cnt, 1); if (sl < MAXSEL) s_idx[sl] = (int)i1; }
        __syncthreads();
    } else {
        // ---------- fallback: stream full slice (never hit for this data) ----------
        const u64x2* sb2 = (const u64x2*)(scores + (size_t)b * LL);
        if (tid == 0) { sh_prefix = 0ULL; sh_r = topk_p[0]; }
        __syncthreads();
        int copy = tid & (NCOPY - 1);
        for (int shift = 56; shift >= 0; shift -= 8) {
            unsigned int dA2 = (unsigned int)(A >> shift) & 255u;
            unsigned int dO2 = (unsigned int)(O >> shift) & 255u;
            if (dA2 == dO2) {
                if (tid == 0) sh_prefix |= ((unsigned long long)dA2 << shift);
                __syncthreads();
                continue;
            }
            for (int i = tid; i < NCOPY * HSTRIDE; i += T) hist[i] = 0;
            __syncthreads();
            unsigned long long prefix = sh_prefix;
            unsigned long long hm = (shift == 56) ? 0ULL : (~0ULL << (shift + 8));
            int r = sh_r;
#pragma unroll
            for (int batch = 0; batch < 2; ++batch) {
                u64x2 p[8];
#pragma unroll
                for (int j = 0; j < 8; ++j) p[j] = sb2[tid + (batch * 8 + j) * T];
#pragma unroll
                for (int j = 0; j < 8; ++j) {
                    if ((p[j].x & hm) == prefix)
                        atomicAdd(&hist[copy * HSTRIDE + ((unsigned)(p[j].x >> shift) & 255u)], 1u);
                    if ((p[j].y & hm) == prefix)
                        atomicAdd(&hist[copy * HSTRIDE + ((unsigned)(p[j].y >> shift) & 255u)], 1u);
                }
            }
            __syncthreads();
            RADIX_SCAN(r)
            if (tid == 0) {
                sh_prefix |= ((unsigned long long)sh_digit << shift);
                sh_r = sh_newr;
            }
            __syncthreads();
        }
        unsigned long long cb = sh_prefix;
        if (tid == 0) s_cnt = 0;
        __syncthreads();
#pragma unroll
        for (int batch = 0; batch < 2; ++batch) {
            u64x2 p[8];
#pragma unroll
            for (int j = 0; j < 8; ++j) p[j] = sb2[tid + (batch * 8 + j) * T];
#pragma unroll
            for (int j = 0; j < 8; ++j) {
                int jj = batch * 8 + j;
                if (p[j].x > cb) { int sl = atomicAdd(&s_cnt, 1); if (sl < MAXSEL) s_idx[sl] = 2 * (tid + jj * T); }
                if (p[j].y > cb) { int sl = atomicAdd(&s_cnt, 1); if (sl < MAXSEL) s_idx[sl] = 2 * (tid + jj * T) + 1; }
            }
        }
        __syncthreads();
    }

    int cnt = s_cnt < MAXSEL ? s_cnt : MAXSEL;
    int g = tid >> 4, lane16 = tid & 15;
    for (int r2 = g; r2 < cnt; r2 += 64) {
        size_t rowOff = ((size_t)b * LL + s_idx[r2]) * DD;
        const f4* vrow = (const f4*)(v + rowOff);
        f4*       orow = (f4*)(out + rowOff);
        orow[lane16] = vrow[lane16];
    }
}

extern "C" void kernel_launch(void* const* d_in, const int* in_sizes, int n_in,
                              void* d_out, int out_size, void* d_ws, size_t ws_size,
                              hipStream_t stream) {
    const float* q = (const float*)d_in[0];
    const float* k = (const float*)d_in[1];
    const float* v = (const float*)d_in[2];
    const int* topk = (const int*)d_in[3];
    float* out = (float*)d_out;

    double* part   = (double*)d_ws;
    double* scores = (double*)((char*)d_ws + 262144);
    char* aux = (char*)d_ws + 262144 + 2097152;
    unsigned long long* gAnd    = (unsigned long long*)aux;
    unsigned long long* gOr     = (unsigned long long*)(aux + 64);
    unsigned int*       gcnt    = (unsigned int*)(aux + 128);
    unsigned long long* candKey = (unsigned long long*)(aux + 256);
    unsigned int*       candIdx = (unsigned int*)(aux + 256 + (size_t)BB * CAP * 8);

    k_reduce_q<<<BB * CHUNKS_Q, 256, 0, stream>>>(q, part, out, gAnd, gOr, gcnt);
    k_scores<<<BB * (LL / 256), 256, 0, stream>>>(k, part, scores, out, gAnd, gOr);
    k_filter<<<BB * 16, 256, 0, stream>>>(scores, gAnd, gOr, topk, gcnt, candKey, candIdx);
    k_select_gather<<<BB, 1024, 0, stream>>>(scores, gAnd, gOr, gcnt, candKey, candIdx, topk, v, out);
}